// Round 4
// baseline (455.240 us; speedup 1.0000x reference)
//
#include <hip/hip_runtime.h>
#include <math.h>

#define N_OBJ 8192
#define N_SR  4096
#define N_F   4096
#define EPSF  1e-8f
#define NB    1024

// Device-wide barrier: grid=1024 blocks, all co-resident (4 blocks/CU via
// __launch_bounds__(256,4)). Arrive-and-spin on a per-barrier counter; agent
// fences handle cross-XCD L2 writeback/invalidate; atomic polls go to the
// coherence point (no stale-L2 spin).
__device__ __forceinline__ void gbar(int* bar, int k) {
    __syncthreads();
    if (threadIdx.x == 0) {
        __threadfence();                       // release
        atomicAdd(&bar[k], 1);
        while (atomicAdd(&bar[k], 0) < NB) __builtin_amdgcn_s_sleep(8);
        __threadfence();                       // acquire
    }
    __syncthreads();
}

__global__ void __launch_bounds__(256, 4) mega(
    const float* __restrict__ obj, const float* __restrict__ sr,
    const float* __restrict__ hv,  const float* __restrict__ fn,
    const int*   __restrict__ hf,  float* __restrict__ out,
    int* __restrict__ bar, float2* __restrict__ pdi,
    float4* __restrict__ Dws, int* __restrict__ hits,
    float4* __restrict__ F, float* __restrict__ part)
{
    const int tid = threadIdx.x;
    const int b   = blockIdx.x;
    __shared__ float4 sbuf[128];               // 2 KB, reused per phase

    // ================= Phase A: NN partials + face table + zero hits =======
    if (tid < 8) hits[b * 8 + tid] = 0;
    if (tid < 4) {                             // 4 faces per block
        const int f = b * 4 + tid;
        const int i0 = hf[3*f], i1 = hf[3*f+1], i2 = hf[3*f+2];
        const float v0x=hv[3*i0], v0y=hv[3*i0+1], v0z=hv[3*i0+2];
        const float v1x=hv[3*i1], v1y=hv[3*i1+1], v1z=hv[3*i1+2];
        const float v2x=hv[3*i2], v2y=hv[3*i2+1], v2z=hv[3*i2+2];
        const float nx=fn[3*f], ny=fn[3*f+1], nz=fn[3*f+2];
        F[4*f+0] = make_float4(nx, ny, nz, v0x*nx + v0y*ny + v0z*nz);
        {
            float ex=v1x-v0x, ey=v1y-v0y, ez=v1z-v0z;
            float cx=ny*ez-nz*ey, cy=nz*ex-nx*ez, cz=nx*ey-ny*ex;
            F[4*f+1] = make_float4(cx, cy, cz, v0x*cx + v0y*cy + v0z*cz);
        }
        {
            float ex=v2x-v1x, ey=v2y-v1y, ez=v2z-v1z;
            float cx=ny*ez-nz*ey, cy=nz*ex-nx*ez, cz=nx*ey-ny*ex;
            F[4*f+2] = make_float4(cx, cy, cz, v1x*cx + v1y*cy + v1z*cz);
        }
        {
            float ex=v0x-v2x, ey=v0y-v2y, ez=v0z-v2z;
            float cx=ny*ez-nz*ey, cy=nz*ex-nx*ez, cz=nx*ey-ny*ex;
            F[4*f+3] = make_float4(cx, cy, cz, v2x*cx + v2y*cy + v2z*cz);
        }
    }
    {
        // block = (obj-group of 512 pts) x (sr-chunk of 64); 2 pts/thread
        const int og = b & 15, sc = b >> 4, sbase = sc * 64;
        if (tid < 64) {
            int j = sbase + tid;
            float sx = sr[3*j], sy = sr[3*j+1], sz = sr[3*j+2];
            sbuf[tid] = make_float4(sx, sy, sz, sx*sx + sy*sy + sz*sz);
        }
        __syncthreads();
        const int p0 = og * 512 + tid, p1 = p0 + 256;
        const float ax = obj[3*p0], ay = obj[3*p0+1], az = obj[3*p0+2];
        const float bx = obj[3*p1], by = obj[3*p1+1], bz = obj[3*p1+2];
        const float aa = ax*ax + ay*ay + az*az;
        const float bb = bx*bx + by*by + bz*bz;
        float bda = INFINITY, bdb = INFINITY;
        int ia = sbase, ib = sbase;
#pragma unroll 8
        for (int j = 0; j < 64; ++j) {
            float4 s = sbuf[j];                // wave-uniform -> LDS broadcast
            float da = fmaf(-2.f, fmaf(s.z, az, fmaf(s.y, ay, s.x*ax)), aa + s.w);
            float db = fmaf(-2.f, fmaf(s.z, bz, fmaf(s.y, by, s.x*bx)), bb + s.w);
            if (da < bda) { bda = da; ia = sbase + j; }   // strict < -> first idx
            if (db < bdb) { bdb = db; ib = sbase + j; }
        }
        pdi[p0 * 64 + sc] = make_float2(bda, __int_as_float(ia));
        pdi[p1 * 64 + sc] = make_float2(bdb, __int_as_float(ib));
    }
    gbar(bar, 0);

    // ================= Phase B: merge 64 partials/pt, D-vector, cmap =======
    {
        const int pt = b * 8 + (tid >> 5), c = tid & 31;
        float2 e0 = pdi[pt * 64 + c];
        float2 e1 = pdi[pt * 64 + 32 + c];
        float bd = e0.x; int bi = __float_as_int(e0.y);
        {
            float d = e1.x; int i = __float_as_int(e1.y);
            if (d < bd || (d == bd && i < bi)) { bd = d; bi = i; }
        }
#pragma unroll
        for (int off = 16; off > 0; off >>= 1) {
            float d = __shfl_down(bd, off, 32);
            int   i = __shfl_down(bi, off, 32);
            if (d < bd || (d == bd && i < bi)) { bd = d; bi = i; }
        }
        if ((tid & 31) == 0) {
            float ox = obj[3*pt], oy = obj[3*pt+1], oz = obj[3*pt+2];
            float dx = sr[3*bi]   - ox;
            float dy = sr[3*bi+1] - oy;
            float dz = sr[3*bi+2] - oz;
            Dws[pt] = make_float4(dx, dy, dz, dx*dx + dy*dy + dz*dz);
            float nn  = sqrtf(fmaxf(bd, 0.f));
            float sig = 1.f / (1.f + expf(-100.f * nn));
            out[1 + pt] = 1.f - 2.f * (sig - 0.5f);
        }
    }
    gbar(bar, 1);

    // ================= Phase C: ray-triangle parity (div-free, 4 pts/thr) ==
    // hit <=> dn>EPS && nm>EPS*dn && min_i(C_i.w*(-dn) + C_i.w_vec) >= 0
    // dn=|denom|, nm=num*sign(denom), w = o*dn + nm*D
    {
        const int pg = b & 7, fc = b >> 3;     // 8 pt-groups x 128 face-chunks
        if (tid < 128) sbuf[tid] = F[fc * 128 + tid];
        __syncthreads();
        float px[4], py[4], pz[4], qx[4], qy[4], qz[4];
        int cnt[4];
#pragma unroll
        for (int k = 0; k < 4; ++k) {
            int p = pg * 1024 + k * 256 + tid;
            px[k] = obj[3*p]; py[k] = obj[3*p+1]; pz[k] = obj[3*p+2];
            float4 D = Dws[p];
            qx[k] = D.x; qy[k] = D.y; qz[k] = D.z;
            cnt[k] = 0;
        }
#pragma unroll 2
        for (int f = 0; f < 32; ++f) {
            const float4 Fn = sbuf[4*f+0];     // broadcast reads
            const float4 C1 = sbuf[4*f+1];
            const float4 C2 = sbuf[4*f+2];
            const float4 C3 = sbuf[4*f+3];
#pragma unroll
            for (int k = 0; k < 4; ++k) {
                float denom = fmaf(Fn.z, qz[k], fmaf(Fn.y, qy[k], Fn.x*qx[k]));
                float num   = Fn.w - fmaf(Fn.z, pz[k], fmaf(Fn.y, py[k], Fn.x*px[k]));
                float dn = fabsf(denom);
                float nm = copysignf(num, num * denom);
                float wx = fmaf(px[k], dn, nm * qx[k]);
                float wy = fmaf(py[k], dn, nm * qy[k]);
                float wz = fmaf(pz[k], dn, nm * qz[k]);
                float q1 = fmaf(-C1.w, dn, fmaf(C1.z, wz, fmaf(C1.y, wy, C1.x*wx)));
                float q2 = fmaf(-C2.w, dn, fmaf(C2.z, wz, fmaf(C2.y, wy, C2.x*wx)));
                float q3 = fmaf(-C3.w, dn, fmaf(C3.z, wz, fmaf(C3.y, wy, C3.x*wx)));
                float m  = fminf(q1, fminf(q2, q3));
                cnt[k] += ((m >= 0.f) && (fmaf(-EPSF, dn, nm) > 0.f) && (dn > EPSF)) ? 1 : 0;
            }
        }
#pragma unroll
        for (int k = 0; k < 4; ++k)
            atomicAdd(&hits[pg * 1024 + k * 256 + tid], cnt[k]);
    }
    gbar(bar, 2);

    // ================= Phase D: pen_dist reduction =========================
    {
        float s = 0.f;
        if (tid < 8) {
            int pt = b * 8 + tid;
            if (hits[pt] & 1) s = Dws[pt].w;
        }
        s += __shfl_down(s, 4, 8);
        s += __shfl_down(s, 2, 8);
        s += __shfl_down(s, 1, 8);
        if (tid == 0) part[b] = s;
    }
    gbar(bar, 3);
    if (b == 0) {                              // deterministic final sum
        float s = part[tid] + part[tid+256] + part[tid+512] + part[tid+768];
#pragma unroll
        for (int off = 32; off > 0; off >>= 1) s += __shfl_down(s, off);
        float* sb = (float*)sbuf;
        if ((tid & 63) == 0) sb[tid >> 6] = s;
        __syncthreads();
        if (tid == 0) out[0] = sqrtf(sb[0] + sb[1] + sb[2] + sb[3] + 1e-12f);
    }
}

extern "C" void kernel_launch(void* const* d_in, const int* in_sizes, int n_in,
                              void* d_out, int out_size, void* d_ws, size_t ws_size,
                              hipStream_t stream) {
    const float* obj = (const float*)d_in[0];
    const float* sr  = (const float*)d_in[1];
    const float* hv  = (const float*)d_in[2];
    const float* fn  = (const float*)d_in[3];
    const int*   hf  = (const int*)d_in[4];
    float* out = (float*)d_out;

    char* ws = (char*)d_ws;
    int*    bar  = (int*)ws;                           // 64 B (memset to 0)
    float2* pdi  = (float2*)(ws + 256);                // 8192*64*8 = 4 MB
    float4* Dws  = (float4*)(ws + 256 + 4194304);      // 128 KB
    int*    hits = (int*)   (ws + 256 + 4194304 + 131072);            // 32 KB
    float4* F    = (float4*)(ws + 256 + 4194304 + 131072 + 32768);    // 256 KB
    float*  part = (float*) (ws + 256 + 4194304 + 131072 + 32768 + 262144); // 4 KB

    hipMemsetAsync(ws, 0, 256, stream);                // zero barrier counters
    mega<<<NB, 256, 0, stream>>>(obj, sr, hv, fn, hf, out,
                                 bar, pdi, Dws, hits, F, part);
}

// Round 5
// 120.413 us; speedup vs baseline: 3.7807x; 3.7807x over previous
//
#include <hip/hip_runtime.h>
#include <math.h>

#define N_OBJ 8192
#define N_SR  4096
#define N_F   4096
#define EPSF  1e-8f

typedef float v2f __attribute__((ext_vector_type(2)));
static __device__ __forceinline__ v2f sp(float x) { v2f r; r.x = x; r.y = x; return r; }
static __device__ __forceinline__ v2f vfma(v2f a, v2f b, v2f c) { return __builtin_elementwise_fma(a, b, c); }
static __device__ __forceinline__ v2f vmin2(v2f a, v2f b) { return __builtin_elementwise_min(a, b); }

// ================= K1: NN (full, block-local) + face table + zero hits ======
// 256 blocks x 256 thr. Each block: stages all sr in LDS (SoA, 48KB),
// computes exact NN for its 32 obj points (32 interleaved sr-slices x 4 pts/thr),
// reduces slices via shuffle + LDS, writes Dws/cmap. Also builds 16 faces.
__global__ void __launch_bounds__(256) nn_all(const float* __restrict__ obj,
                                              const float* __restrict__ sr,
                                              const float* __restrict__ hv,
                                              const float* __restrict__ fn,
                                              const int* __restrict__ hf,
                                              float* __restrict__ out,
                                              float4* __restrict__ Dws,
                                              int* __restrict__ hits,
                                              float4* __restrict__ F) {
    __shared__ float sx[N_SR], sy[N_SR], sz[N_SR];   // 48 KB
    __shared__ float2 red[4][32];                     // 1 KB
    const int tid = threadIdx.x, b = blockIdx.x;

#pragma unroll
    for (int it = 0; it < 16; ++it) {
        int idx = it * 256 + tid;
        sx[idx] = sr[3 * idx];
        sy[idx] = sr[3 * idx + 1];
        sz[idx] = sr[3 * idx + 2];
    }
    if (tid < 32) hits[b * 32 + tid] = 0;
    if (tid < 16) {                                   // 16 faces per block
        const int f = b * 16 + tid;
        const int i0 = hf[3*f], i1 = hf[3*f+1], i2 = hf[3*f+2];
        const float v0x = hv[3*i0], v0y = hv[3*i0+1], v0z = hv[3*i0+2];
        const float v1x = hv[3*i1], v1y = hv[3*i1+1], v1z = hv[3*i1+2];
        const float v2x = hv[3*i2], v2y = hv[3*i2+1], v2z = hv[3*i2+2];
        const float nx = fn[3*f], ny = fn[3*f+1], nz = fn[3*f+2];
        F[4*f+0] = make_float4(nx, ny, nz, v0x*nx + v0y*ny + v0z*nz);
        {
            float ex = v1x-v0x, ey = v1y-v0y, ez = v1z-v0z;
            float cx = ny*ez-nz*ey, cy = nz*ex-nx*ez, cz = nx*ey-ny*ex;
            F[4*f+1] = make_float4(cx, cy, cz, v0x*cx + v0y*cy + v0z*cz);
        }
        {
            float ex = v2x-v1x, ey = v2y-v1y, ez = v2z-v1z;
            float cx = ny*ez-nz*ey, cy = nz*ex-nx*ez, cz = nx*ey-ny*ex;
            F[4*f+2] = make_float4(cx, cy, cz, v1x*cx + v1y*cy + v1z*cz);
        }
        {
            float ex = v0x-v2x, ey = v0y-v2y, ez = v0z-v2z;
            float cx = ny*ez-nz*ey, cy = nz*ex-nx*ez, cz = nx*ey-ny*ex;
            F[4*f+3] = make_float4(cx, cy, cz, v2x*cx + v2y*cy + v2z*cz);
        }
    }
    __syncthreads();

    // thread (w, pp, sl): slice s = w*8+sl of 32 (interleaved: global = j*32+s),
    // points pbase..pbase+3
    const int w = tid >> 6, lane = tid & 63;
    const int pp = lane >> 3, sl = lane & 7;
    const int s = w * 8 + sl;
    const int pbase = b * 32 + pp * 4;

    float ox[4], oy[4], oz[4];
#pragma unroll
    for (int k = 0; k < 4; ++k) {
        int p = pbase + k;
        ox[k] = obj[3*p]; oy[k] = obj[3*p+1]; oz[k] = obj[3*p+2];
    }
    float bd[4]; int bj[4];
#pragma unroll
    for (int k = 0; k < 4; ++k) { bd[k] = INFINITY; bj[k] = 0; }

#pragma unroll 4
    for (int j = 0; j < 128; ++j) {
        int e = j * 32 + s;                           // bank = s -> conflict-free
        float vx = sx[e], vy = sy[e], vz = sz[e];
#pragma unroll
        for (int k = 0; k < 4; ++k) {
            float dx = vx - ox[k], dy = vy - oy[k], dz = vz - oz[k];
            float d2 = fmaf(dx, dx, fmaf(dy, dy, dz * dz));
            if (d2 < bd[k]) { bd[k] = d2; bj[k] = j; }   // strict < -> lowest j
        }
    }
    int bi[4];
#pragma unroll
    for (int k = 0; k < 4; ++k) bi[k] = bj[k] * 32 + s;
#pragma unroll
    for (int off = 4; off; off >>= 1) {               // reduce 8 slices in-wave
#pragma unroll
        for (int k = 0; k < 4; ++k) {
            float d = __shfl_down(bd[k], off, 8);
            int   i = __shfl_down(bi[k], off, 8);
            if (d < bd[k] || (d == bd[k] && i < bi[k])) { bd[k] = d; bi[k] = i; }
        }
    }
    if (sl == 0) {
#pragma unroll
        for (int k = 0; k < 4; ++k)
            red[w][pp * 4 + k] = make_float2(bd[k], __int_as_float(bi[k]));
    }
    __syncthreads();
    if (tid < 32) {                                   // cross-wave final merge
        float2 e0 = red[0][tid];
        float bdf = e0.x; int bif = __float_as_int(e0.y);
#pragma unroll
        for (int w2 = 1; w2 < 4; ++w2) {
            float2 e2 = red[w2][tid];
            float d = e2.x; int i = __float_as_int(e2.y);
            if (d < bdf || (d == bdf && i < bif)) { bdf = d; bif = i; }
        }
        int p = b * 32 + tid;
        float pox = obj[3*p], poy = obj[3*p+1], poz = obj[3*p+2];
        float dx = sx[bif] - pox, dy = sy[bif] - poy, dz = sz[bif] - poz;
        Dws[p] = make_float4(dx, dy, dz, dx*dx + dy*dy + dz*dz);
        float nn = sqrtf(fmaxf(bdf, 0.f));
        float sig = 1.f / (1.f + expf(-100.f * nn));
        out[1 + p] = 1.f - 2.f * (sig - 0.5f);
    }
}

// ================= K2: ray-triangle parity, packed fp32 (v_pk_fma) ==========
// 256 blocks = 4 pt-groups x 64 face-chunks; 8 pts/thread as 4 float2 pairs.
// hit <=> min(q1,q2,q3, nm-EPS*dn, dn-EPS) >= 0 with dn=|denom|,
// nm=num*sign(denom), w = o*dn + nm*D  (division-free, sign-exact)
#define RFC 64
__global__ void __launch_bounds__(256) ray_count(const float* __restrict__ obj,
                                                 const float4* __restrict__ Dws,
                                                 const float4* __restrict__ F,
                                                 int* __restrict__ hits) {
    __shared__ float4 sF[RFC * 4];                    // 4 KB
    const int tid = threadIdx.x;
    const int pg = blockIdx.x & 3, fc = blockIdx.x >> 2;
    {
        const float* Ff = (const float*)(F + (size_t)fc * RFC * 4);
        float* sf = (float*)sF;
#pragma unroll
        for (int i = 0; i < RFC * 16 / 256; ++i)
            sf[i * 256 + tid] = Ff[i * 256 + tid];
    }
    __syncthreads();

    v2f px[4], py[4], pz[4], qx[4], qy[4], qz[4];
    int cnt[8];
#pragma unroll
    for (int g = 0; g < 4; ++g) {
#pragma unroll
        for (int h = 0; h < 2; ++h) {
            int p = pg * 2048 + (g * 2 + h) * 256 + tid;
            px[g][h] = obj[3*p]; py[g][h] = obj[3*p+1]; pz[g][h] = obj[3*p+2];
            float4 D = Dws[p];
            qx[g][h] = D.x; qy[g][h] = D.y; qz[g][h] = D.z;
            cnt[g * 2 + h] = 0;
        }
    }

#pragma unroll 2
    for (int f = 0; f < RFC; ++f) {
        const float4 Fn = sF[4*f+0];                  // wave-uniform -> broadcast
        const float4 C1 = sF[4*f+1];
        const float4 C2 = sF[4*f+2];
        const float4 C3 = sF[4*f+3];
#pragma unroll
        for (int g = 0; g < 4; ++g) {
            v2f denom = vfma(sp(Fn.z), qz[g], vfma(sp(Fn.y), qy[g], sp(Fn.x) * qx[g]));
            v2f num   = sp(Fn.w) - vfma(sp(Fn.z), pz[g], vfma(sp(Fn.y), py[g], sp(Fn.x) * px[g]));
            v2f dn = __builtin_elementwise_abs(denom);
            v2f nm = __builtin_elementwise_copysign(num, num * denom);
            v2f wx = vfma(px[g], dn, nm * qx[g]);
            v2f wy = vfma(py[g], dn, nm * qy[g]);
            v2f wz = vfma(pz[g], dn, nm * qz[g]);
            v2f q1 = vfma(sp(-C1.w), dn, vfma(sp(C1.z), wz, vfma(sp(C1.y), wy, sp(C1.x) * wx)));
            v2f q2 = vfma(sp(-C2.w), dn, vfma(sp(C2.z), wz, vfma(sp(C2.y), wy, sp(C2.x) * wx)));
            v2f q3 = vfma(sp(-C3.w), dn, vfma(sp(C3.z), wz, vfma(sp(C3.y), wy, sp(C3.x) * wx)));
            v2f mm = vmin2(q1, vmin2(q2, q3));
            mm = vmin2(mm, vfma(sp(-EPSF), dn, nm));  // t>EPS  (boundary-equal ok)
            mm = vmin2(mm, dn - sp(EPSF));            // dn>EPS (boundary-equal ok)
            cnt[g * 2 + 0] += (mm[0] >= 0.f) ? 1 : 0;
            cnt[g * 2 + 1] += (mm[1] >= 0.f) ? 1 : 0;
        }
    }
#pragma unroll
    for (int g = 0; g < 4; ++g) {
        atomicAdd(&hits[pg * 2048 + (g * 2 + 0) * 256 + tid], cnt[g * 2 + 0]);
        atomicAdd(&hits[pg * 2048 + (g * 2 + 1) * 256 + tid], cnt[g * 2 + 1]);
    }
}

// ================= K3: pen_dist reduction (deterministic, 1 block) ==========
__global__ void __launch_bounds__(256) finalize(const float4* __restrict__ Dws,
                                                const int* __restrict__ hits,
                                                float* __restrict__ out) {
    __shared__ float wsum[4];
    const int tid = threadIdx.x;
    float s = 0.f;
#pragma unroll 8
    for (int k = tid; k < N_OBJ; k += 256) {
        if (hits[k] & 1) s += Dws[k].w;
    }
#pragma unroll
    for (int off = 32; off > 0; off >>= 1) s += __shfl_down(s, off);
    if ((tid & 63) == 0) wsum[tid >> 6] = s;
    __syncthreads();
    if (tid == 0) {
        out[0] = sqrtf(wsum[0] + wsum[1] + wsum[2] + wsum[3] + 1e-12f);
    }
}

extern "C" void kernel_launch(void* const* d_in, const int* in_sizes, int n_in,
                              void* d_out, int out_size, void* d_ws, size_t ws_size,
                              hipStream_t stream) {
    const float* obj = (const float*)d_in[0];
    const float* sr  = (const float*)d_in[1];
    const float* hv  = (const float*)d_in[2];
    const float* fn  = (const float*)d_in[3];
    const int*   hf  = (const int*)d_in[4];
    float* out = (float*)d_out;

    char* ws = (char*)d_ws;
    float4* Dws  = (float4*)(ws + 0);                 // 8192*16   = 128 KB
    int*    hits = (int*)  (ws + 131072);             // 8192*4    =  32 KB
    float4* F    = (float4*)(ws + 163840);            // 4096*4*16 = 256 KB

    nn_all<<<N_OBJ / 32, 256, 0, stream>>>(obj, sr, hv, fn, hf, out, Dws, hits, F);
    ray_count<<<256, 256, 0, stream>>>(obj, Dws, F, hits);
    finalize<<<1, 256, 0, stream>>>(Dws, hits, out);
}

// Round 6
// 115.449 us; speedup vs baseline: 3.9432x; 1.0430x over previous
//
#include <hip/hip_runtime.h>
#include <math.h>

#define N_OBJ 8192
#define N_SR  4096
#define N_F   4096
#define EPSF  1e-8f

typedef float v2f __attribute__((ext_vector_type(2)));
static __device__ __forceinline__ v2f sp(float x) { v2f r; r.x = x; r.y = x; return r; }
static __device__ __forceinline__ v2f vfma(v2f a, v2f b, v2f c) { return __builtin_elementwise_fma(a, b, c); }
static __device__ __forceinline__ v2f vmin2(v2f a, v2f b) { return __builtin_elementwise_min(a, b); }

// ================= K1: NN (packed fp32) + face table + zero hits/done =======
// 512 blocks x 256. Block stages all 4096 sr as pair-packed SoA (64 KB LDS).
// Each wave owns 4 obj points; 64 lanes = 64 pair-slices; 32 steps/lane.
// argmin tracked on shifted d2' = ss - 2*dot (aa added after reduction).
__global__ void __launch_bounds__(256) nn_all(const float* __restrict__ obj,
                                              const float* __restrict__ sr,
                                              const float* __restrict__ hv,
                                              const float* __restrict__ fn,
                                              const int* __restrict__ hf,
                                              float* __restrict__ out,
                                              float4* __restrict__ Dws,
                                              int* __restrict__ hits,
                                              float4* __restrict__ F,
                                              int* __restrict__ done) {
    __shared__ float4 pXY[N_SR / 2];               // (x0,x1,y0,y1)  32 KB
    __shared__ float4 pZS[N_SR / 2];               // (z0,z1,ss0,ss1) 32 KB
    const int tid = threadIdx.x, b = blockIdx.x;

    const float2* sr2 = (const float2*)sr;
#pragma unroll
    for (int i = 0; i < 8; ++i) {
        int e = i * 256 + tid;
        float2 A = sr2[3 * e], B = sr2[3 * e + 1], C = sr2[3 * e + 2];
        float x0 = A.x, y0 = A.y, z0 = B.x, x1 = B.y, y1 = C.x, z1 = C.y;
        float s0 = fmaf(x0, x0, fmaf(y0, y0, z0 * z0));
        float s1 = fmaf(x1, x1, fmaf(y1, y1, z1 * z1));
        pXY[e] = make_float4(x0, x1, y0, y1);
        pZS[e] = make_float4(z0, z1, s0, s1);
    }
    if (tid < 16) hits[b * 16 + tid] = 0;
    if (b == 0 && tid == 0) done[0] = 0;
    if (tid < 8) {                                 // 8 faces per block
        const int f = b * 8 + tid;
        const int i0 = hf[3*f], i1 = hf[3*f+1], i2 = hf[3*f+2];
        const float v0x = hv[3*i0], v0y = hv[3*i0+1], v0z = hv[3*i0+2];
        const float v1x = hv[3*i1], v1y = hv[3*i1+1], v1z = hv[3*i1+2];
        const float v2x = hv[3*i2], v2y = hv[3*i2+1], v2z = hv[3*i2+2];
        const float nx = fn[3*f], ny = fn[3*f+1], nz = fn[3*f+2];
        F[4*f+0] = make_float4(nx, ny, nz, v0x*nx + v0y*ny + v0z*nz);
        {
            float ex = v1x-v0x, ey = v1y-v0y, ez = v1z-v0z;
            float cx = ny*ez-nz*ey, cy = nz*ex-nx*ez, cz = nx*ey-ny*ex;
            F[4*f+1] = make_float4(cx, cy, cz, v0x*cx + v0y*cy + v0z*cz);
        }
        {
            float ex = v2x-v1x, ey = v2y-v1y, ez = v2z-v1z;
            float cx = ny*ez-nz*ey, cy = nz*ex-nx*ez, cz = nx*ey-ny*ex;
            F[4*f+2] = make_float4(cx, cy, cz, v1x*cx + v1y*cy + v1z*cz);
        }
        {
            float ex = v0x-v2x, ey = v0y-v2y, ez = v0z-v2z;
            float cx = ny*ez-nz*ey, cy = nz*ex-nx*ez, cz = nx*ey-ny*ex;
            F[4*f+3] = make_float4(cx, cy, cz, v2x*cx + v2y*cy + v2z*cz);
        }
    }
    __syncthreads();

    const int w = tid >> 6, lane = tid & 63;
    const int pbase = b * 16 + w * 4;              // wave-uniform -> s_load

    float ox[4], oy[4], oz[4], aa[4];
#pragma unroll
    for (int k = 0; k < 4; ++k) {
        int p = pbase + k;
        ox[k] = obj[3*p]; oy[k] = obj[3*p+1]; oz[k] = obj[3*p+2];
        aa[k] = fmaf(ox[k], ox[k], fmaf(oy[k], oy[k], oz[k] * oz[k]));
    }
    float b0[4], b1[4]; int i0[4], i1[4];
#pragma unroll
    for (int k = 0; k < 4; ++k) { b0[k] = b1[k] = INFINITY; i0[k] = 0; i1[k] = 1; }

    int e2 = lane * 2;                             // global idx of half-0
#pragma unroll 4
    for (int step = 0; step < 32; ++step) {
        int e = step * 64 + lane;
        float4 A = pXY[e];                         // stride-16B -> conflict-free
        float4 B = pZS[e];
        v2f X; X.x = A.x; X.y = A.y;
        v2f Y; Y.x = A.z; Y.y = A.w;
        v2f Z; Z.x = B.x; Z.y = B.y;
        v2f SS; SS.x = B.z; SS.y = B.w;
#pragma unroll
        for (int k = 0; k < 4; ++k) {
            v2f d  = vfma(Z, sp(oz[k]), vfma(Y, sp(oy[k]), X * sp(ox[k])));
            v2f d2 = vfma(d, sp(-2.f), SS);        // shifted by -aa (const/pt)
            bool c0 = d2.x < b0[k];
            bool c1 = d2.y < b1[k];
            b0[k] = c0 ? d2.x : b0[k];  i0[k] = c0 ? e2     : i0[k];
            b1[k] = c1 ? d2.y : b1[k];  i1[k] = c1 ? e2 + 1 : i1[k];
        }
        e2 += 128;
    }
#pragma unroll
    for (int k = 0; k < 4; ++k) {
        float bd = b0[k]; int bi = i0[k];
        if (b1[k] < bd || (b1[k] == bd && i1[k] < bi)) { bd = b1[k]; bi = i1[k]; }
#pragma unroll
        for (int off = 32; off > 0; off >>= 1) {
            float d = __shfl_down(bd, off);
            int   i = __shfl_down(bi, off);
            if (d < bd || (d == bd && i < bi)) { bd = d; bi = i; }
        }
        if (lane == 0) {
            int p = pbase + k;
            float4 A = pXY[bi >> 1];
            float4 B = pZS[bi >> 1];
            int h = bi & 1;
            float sx = h ? A.y : A.x;
            float sy = h ? A.w : A.z;
            float sz = h ? B.y : B.x;
            float dx = sx - ox[k], dy = sy - oy[k], dz = sz - oz[k];
            Dws[p] = make_float4(dx, dy, dz, fmaf(dx, dx, fmaf(dy, dy, dz * dz)));
            float nn  = sqrtf(fmaxf(bd + aa[k], 0.f));
            float sig = 1.f / (1.f + expf(-100.f * nn));
            out[1 + p] = 1.f - 2.f * (sig - 0.5f);
        }
    }
}

// ================= K2: ray parity (packed) + fused last-block finalize ======
// 512 blocks = 4 pt-groups x 128 face-chunks (RFC=32); 8 pts/thread (4 v2f).
// hit <=> min(q1,q2,q3, nm-EPS*dn, dn-EPS) >= 0; dn=|denom|,
// nm=num*sign(denom), w = o*dn + nm*D (division-free, sign-exact).
#define RFC 32
#define RAY_NB 512
__global__ void __launch_bounds__(256) ray_count(const float* __restrict__ obj,
                                                 const float4* __restrict__ Dws,
                                                 const float4* __restrict__ F,
                                                 int* __restrict__ hits,
                                                 int* __restrict__ done,
                                                 float* __restrict__ out) {
    __shared__ float4 sF[RFC * 4];                 // 2 KB
    __shared__ float wsum[4];
    __shared__ int lastf;
    const int tid = threadIdx.x;
    const int pg = blockIdx.x & 3, fc = blockIdx.x >> 2;

    v2f px[4], py[4], pz[4], qx[4], qy[4], qz[4];
    int cnt[8];
#pragma unroll
    for (int g = 0; g < 4; ++g) {
#pragma unroll
        for (int h = 0; h < 2; ++h) {
            int p = pg * 2048 + (g * 2 + h) * 256 + tid;
            px[g][h] = obj[3*p]; py[g][h] = obj[3*p+1]; pz[g][h] = obj[3*p+2];
            float4 D = Dws[p];
            qx[g][h] = D.x; qy[g][h] = D.y; qz[g][h] = D.z;
            cnt[g * 2 + h] = 0;
        }
    }
    {
        const float* Ff = (const float*)(F + (size_t)fc * RFC * 4);
        float* sf = (float*)sF;
#pragma unroll
        for (int i = 0; i < RFC * 16 / 256; ++i)
            sf[i * 256 + tid] = Ff[i * 256 + tid];
    }
    __syncthreads();

#pragma unroll 2
    for (int f = 0; f < RFC; ++f) {
        const float4 Fn = sF[4*f+0];               // wave-uniform -> broadcast
        const float4 C1 = sF[4*f+1];
        const float4 C2 = sF[4*f+2];
        const float4 C3 = sF[4*f+3];
#pragma unroll
        for (int g = 0; g < 4; ++g) {
            v2f denom = vfma(sp(Fn.z), qz[g], vfma(sp(Fn.y), qy[g], sp(Fn.x) * qx[g]));
            v2f num   = sp(Fn.w) - vfma(sp(Fn.z), pz[g], vfma(sp(Fn.y), py[g], sp(Fn.x) * px[g]));
            v2f dn = __builtin_elementwise_abs(denom);
            v2f nm = __builtin_elementwise_copysign(num, num * denom);
            v2f wx = vfma(px[g], dn, nm * qx[g]);
            v2f wy = vfma(py[g], dn, nm * qy[g]);
            v2f wz = vfma(pz[g], dn, nm * qz[g]);
            v2f q1 = vfma(sp(-C1.w), dn, vfma(sp(C1.z), wz, vfma(sp(C1.y), wy, sp(C1.x) * wx)));
            v2f q2 = vfma(sp(-C2.w), dn, vfma(sp(C2.z), wz, vfma(sp(C2.y), wy, sp(C2.x) * wx)));
            v2f q3 = vfma(sp(-C3.w), dn, vfma(sp(C3.z), wz, vfma(sp(C3.y), wy, sp(C3.x) * wx)));
            v2f mm = vmin2(q1, vmin2(q2, q3));
            mm = vmin2(mm, vfma(sp(-EPSF), dn, nm));   // t > EPS
            mm = vmin2(mm, dn - sp(EPSF));             // dn > EPS
            cnt[g * 2 + 0] += (mm[0] >= 0.f) ? 1 : 0;
            cnt[g * 2 + 1] += (mm[1] >= 0.f) ? 1 : 0;
        }
    }
#pragma unroll
    for (int g = 0; g < 8; ++g)
        atomicAdd(&hits[pg * 2048 + g * 256 + tid], cnt[g]);

    // -------- last-block-done finalize (deterministic) --------
    __syncthreads();                               // drains vmcnt (atomics done)
    if (tid == 0) {
        __threadfence();
        lastf = (atomicAdd(done, 1) == RAY_NB - 1) ? 1 : 0;
    }
    __syncthreads();
    if (lastf) {
        float s = 0.f;
#pragma unroll 8
        for (int k = tid; k < N_OBJ; k += 256) {
            int h = atomicAdd(&hits[k], 0);        // coherent read (skip stale L2)
            if (h & 1) s += Dws[k].w;
        }
#pragma unroll
        for (int off = 32; off > 0; off >>= 1) s += __shfl_down(s, off);
        if ((tid & 63) == 0) wsum[tid >> 6] = s;
        __syncthreads();
        if (tid == 0)
            out[0] = sqrtf(wsum[0] + wsum[1] + wsum[2] + wsum[3] + 1e-12f);
    }
}

extern "C" void kernel_launch(void* const* d_in, const int* in_sizes, int n_in,
                              void* d_out, int out_size, void* d_ws, size_t ws_size,
                              hipStream_t stream) {
    const float* obj = (const float*)d_in[0];
    const float* sr  = (const float*)d_in[1];
    const float* hv  = (const float*)d_in[2];
    const float* fn  = (const float*)d_in[3];
    const int*   hf  = (const int*)d_in[4];
    float* out = (float*)d_out;

    char* ws = (char*)d_ws;
    float4* Dws  = (float4*)(ws + 0);              // 8192*16   = 128 KB
    int*    hits = (int*)  (ws + 131072);          // 8192*4    =  32 KB
    float4* F    = (float4*)(ws + 163840);         // 4096*4*16 = 256 KB
    int*    done = (int*)  (ws + 425984);          // 4 B

    nn_all<<<512, 256, 0, stream>>>(obj, sr, hv, fn, hf, out, Dws, hits, F, done);
    ray_count<<<RAY_NB, 256, 0, stream>>>(obj, Dws, F, hits, done, out);
}

// Round 7
// 114.697 us; speedup vs baseline: 3.9691x; 1.0066x over previous
//
#include <hip/hip_runtime.h>
#include <math.h>

#define N_OBJ 8192
#define N_SR  4096
#define N_F   4096
#define EPSF  1e-8f

typedef float v2f __attribute__((ext_vector_type(2)));
static __device__ __forceinline__ v2f sp(float x) { v2f r; r.x = x; r.y = x; return r; }
static __device__ __forceinline__ v2f vfma(v2f a, v2f b, v2f c) { return __builtin_elementwise_fma(a, b, c); }
static __device__ __forceinline__ v2f vmin2(v2f a, v2f b) { return __builtin_elementwise_min(a, b); }

// ================= K1: NN (packed fp32) + face table + zero done ============
// 512 blocks x 256. Block stages all 4096 sr as pair-packed SoA (64 KB LDS).
// Each wave owns 4 obj points; 64 lanes = 64 pair-slices; 32 steps/lane.
// argmin tracked on shifted d2' = ss - 2*dot (aa added after reduction).
__global__ void __launch_bounds__(256) nn_all(const float* __restrict__ obj,
                                              const float* __restrict__ sr,
                                              const float* __restrict__ hv,
                                              const float* __restrict__ fn,
                                              const int* __restrict__ hf,
                                              float* __restrict__ out,
                                              float4* __restrict__ Dws,
                                              float4* __restrict__ F,
                                              int* __restrict__ done) {
    __shared__ float4 pXY[N_SR / 2];               // (x0,x1,y0,y1)  32 KB
    __shared__ float4 pZS[N_SR / 2];               // (z0,z1,ss0,ss1) 32 KB
    const int tid = threadIdx.x, b = blockIdx.x;

    const float2* sr2 = (const float2*)sr;
#pragma unroll
    for (int i = 0; i < 8; ++i) {
        int e = i * 256 + tid;
        float2 A = sr2[3 * e], B = sr2[3 * e + 1], C = sr2[3 * e + 2];
        float x0 = A.x, y0 = A.y, z0 = B.x, x1 = B.y, y1 = C.x, z1 = C.y;
        float s0 = fmaf(x0, x0, fmaf(y0, y0, z0 * z0));
        float s1 = fmaf(x1, x1, fmaf(y1, y1, z1 * z1));
        pXY[e] = make_float4(x0, x1, y0, y1);
        pZS[e] = make_float4(z0, z1, s0, s1);
    }
    if (b == 0 && tid == 0) done[0] = 0;
    if (tid < 8) {                                 // 8 faces per block
        const int f = b * 8 + tid;
        const int i0 = hf[3*f], i1 = hf[3*f+1], i2 = hf[3*f+2];
        const float v0x = hv[3*i0], v0y = hv[3*i0+1], v0z = hv[3*i0+2];
        const float v1x = hv[3*i1], v1y = hv[3*i1+1], v1z = hv[3*i1+2];
        const float v2x = hv[3*i2], v2y = hv[3*i2+1], v2z = hv[3*i2+2];
        const float nx = fn[3*f], ny = fn[3*f+1], nz = fn[3*f+2];
        F[4*f+0] = make_float4(nx, ny, nz, v0x*nx + v0y*ny + v0z*nz);
        {
            float ex = v1x-v0x, ey = v1y-v0y, ez = v1z-v0z;
            float cx = ny*ez-nz*ey, cy = nz*ex-nx*ez, cz = nx*ey-ny*ex;
            F[4*f+1] = make_float4(cx, cy, cz, v0x*cx + v0y*cy + v0z*cz);
        }
        {
            float ex = v2x-v1x, ey = v2y-v1y, ez = v2z-v1z;
            float cx = ny*ez-nz*ey, cy = nz*ex-nx*ez, cz = nx*ey-ny*ex;
            F[4*f+2] = make_float4(cx, cy, cz, v1x*cx + v1y*cy + v1z*cz);
        }
        {
            float ex = v0x-v2x, ey = v0y-v2y, ez = v0z-v2z;
            float cx = ny*ez-nz*ey, cy = nz*ex-nx*ez, cz = nx*ey-ny*ex;
            F[4*f+3] = make_float4(cx, cy, cz, v2x*cx + v2y*cy + v2z*cz);
        }
    }
    __syncthreads();

    const int w = tid >> 6, lane = tid & 63;
    const int pbase = b * 16 + w * 4;              // wave-uniform -> s_load

    float ox[4], oy[4], oz[4], aa[4];
#pragma unroll
    for (int k = 0; k < 4; ++k) {
        int p = pbase + k;
        ox[k] = obj[3*p]; oy[k] = obj[3*p+1]; oz[k] = obj[3*p+2];
        aa[k] = fmaf(ox[k], ox[k], fmaf(oy[k], oy[k], oz[k] * oz[k]));
    }
    float b0[4], b1[4]; int i0[4], i1[4];
#pragma unroll
    for (int k = 0; k < 4; ++k) { b0[k] = b1[k] = INFINITY; i0[k] = 0; i1[k] = 1; }

    int e2 = lane * 2;                             // global idx of half-0
#pragma unroll 4
    for (int step = 0; step < 32; ++step) {
        int e = step * 64 + lane;
        float4 A = pXY[e];                         // 16B stride -> conflict-free
        float4 B = pZS[e];
        v2f X; X.x = A.x; X.y = A.y;
        v2f Y; Y.x = A.z; Y.y = A.w;
        v2f Z; Z.x = B.x; Z.y = B.y;
        v2f SS; SS.x = B.z; SS.y = B.w;
#pragma unroll
        for (int k = 0; k < 4; ++k) {
            v2f d  = vfma(Z, sp(oz[k]), vfma(Y, sp(oy[k]), X * sp(ox[k])));
            v2f d2 = vfma(d, sp(-2.f), SS);        // shifted by -aa (const/pt)
            bool c0 = d2.x < b0[k];
            bool c1 = d2.y < b1[k];
            b0[k] = c0 ? d2.x : b0[k];  i0[k] = c0 ? e2     : i0[k];
            b1[k] = c1 ? d2.y : b1[k];  i1[k] = c1 ? e2 + 1 : i1[k];
        }
        e2 += 128;
    }
#pragma unroll
    for (int k = 0; k < 4; ++k) {
        float bd = b0[k]; int bi = i0[k];
        if (b1[k] < bd || (b1[k] == bd && i1[k] < bi)) { bd = b1[k]; bi = i1[k]; }
#pragma unroll
        for (int off = 32; off > 0; off >>= 1) {
            float d = __shfl_down(bd, off);
            int   i = __shfl_down(bi, off);
            if (d < bd || (d == bd && i < bi)) { bd = d; bi = i; }
        }
        if (lane == 0) {
            int p = pbase + k;
            float4 A = pXY[bi >> 1];
            float4 B = pZS[bi >> 1];
            int h = bi & 1;
            float sx = h ? A.y : A.x;
            float sy = h ? A.w : A.z;
            float sz = h ? B.y : B.x;
            float dx = sx - ox[k], dy = sy - oy[k], dz = sz - oz[k];
            Dws[p] = make_float4(dx, dy, dz, fmaf(dx, dx, fmaf(dy, dy, dz * dz)));
            float nn  = sqrtf(fmaxf(bd + aa[k], 0.f));
            float sig = 1.f / (1.f + expf(-100.f * nn));
            out[1 + p] = 1.f - 2.f * (sig - 0.5f);
        }
    }
}

// ================= K2: ray parity -> per-chunk byte counts (NO atomics) =====
// 512 blocks = 8 pt-groups x 64 face-chunks (RFC=64, 4 KB LDS); 4 pts/thread.
// hit <=> min(q1,q2,q3, nm-EPS*dn, dn-EPS) >= 0; dn=|denom|,
// nm=num*sign(denom), w = o*dn + nm*D (division-free, sign-exact).
// One-face register lookahead keeps 4 ds_read_b128 in flight behind compute.
#define RFC 64
__global__ void __launch_bounds__(256) ray_count(const float* __restrict__ obj,
                                                 const float4* __restrict__ Dws,
                                                 const float4* __restrict__ F,
                                                 unsigned char* __restrict__ pcount) {
    __shared__ float4 sF[RFC * 4];                 // 4 KB
    const int tid = threadIdx.x;
    const int pg = blockIdx.x & 7, fc = blockIdx.x >> 3;

    v2f px[2], py[2], pz[2], qx[2], qy[2], qz[2];
    int cnt[4];
#pragma unroll
    for (int g = 0; g < 2; ++g) {
#pragma unroll
        for (int h = 0; h < 2; ++h) {
            int p = pg * 1024 + (g * 2 + h) * 256 + tid;
            px[g][h] = obj[3*p]; py[g][h] = obj[3*p+1]; pz[g][h] = obj[3*p+2];
            float4 D = Dws[p];
            qx[g][h] = D.x; qy[g][h] = D.y; qz[g][h] = D.z;
            cnt[g * 2 + h] = 0;
        }
    }
    {
        const float* Ff = (const float*)(F + (size_t)fc * RFC * 4);
        float* sf = (float*)sF;
#pragma unroll
        for (int i = 0; i < RFC * 16 / 256; ++i)
            sf[i * 256 + tid] = Ff[i * 256 + tid];
    }
    __syncthreads();

    float4 nF0 = sF[0], nF1 = sF[1], nF2 = sF[2], nF3 = sF[3];
#pragma unroll 4
    for (int f = 0; f < RFC; ++f) {
        const float4 Fn = nF0, C1 = nF1, C2 = nF2, C3 = nF3;
        if (f + 1 < RFC) {                         // prefetch next face
            nF0 = sF[4*f+4]; nF1 = sF[4*f+5]; nF2 = sF[4*f+6]; nF3 = sF[4*f+7];
        }
#pragma unroll
        for (int g = 0; g < 2; ++g) {
            v2f denom = vfma(sp(Fn.z), qz[g], vfma(sp(Fn.y), qy[g], sp(Fn.x) * qx[g]));
            v2f num   = sp(Fn.w) - vfma(sp(Fn.z), pz[g], vfma(sp(Fn.y), py[g], sp(Fn.x) * px[g]));
            v2f dn = __builtin_elementwise_abs(denom);
            v2f nm = __builtin_elementwise_copysign(num, num * denom);
            v2f wx = vfma(px[g], dn, nm * qx[g]);
            v2f wy = vfma(py[g], dn, nm * qy[g]);
            v2f wz = vfma(pz[g], dn, nm * qz[g]);
            v2f q1 = vfma(sp(-C1.w), dn, vfma(sp(C1.z), wz, vfma(sp(C1.y), wy, sp(C1.x) * wx)));
            v2f q2 = vfma(sp(-C2.w), dn, vfma(sp(C2.z), wz, vfma(sp(C2.y), wy, sp(C2.x) * wx)));
            v2f q3 = vfma(sp(-C3.w), dn, vfma(sp(C3.z), wz, vfma(sp(C3.y), wy, sp(C3.x) * wx)));
            v2f mm = vmin2(q1, vmin2(q2, q3));
            mm = vmin2(mm, vfma(sp(-EPSF), dn, nm));   // t > EPS
            mm = vmin2(mm, dn - sp(EPSF));             // dn > EPS
            cnt[g * 2 + 0] += (mm[0] >= 0.f) ? 1 : 0;
            cnt[g * 2 + 1] += (mm[1] >= 0.f) ? 1 : 0;
        }
    }
#pragma unroll
    for (int g = 0; g < 4; ++g)                    // coalesced byte stores
        pcount[(size_t)fc * N_OBJ + pg * 1024 + g * 256 + tid] = (unsigned char)cnt[g];
}

// ================= K3: parity + pen_dist (32 blocks, done-counter final) ====
__global__ void __launch_bounds__(256) finalize(const float4* __restrict__ Dws,
                                                const unsigned char* __restrict__ pcount,
                                                float* __restrict__ fpart,
                                                int* __restrict__ done,
                                                float* __restrict__ out) {
    __shared__ float wsum[4];
    __shared__ int lastf;
    const int tid = threadIdx.x;
    const int pt = blockIdx.x * 256 + tid;

    int c = 0;
#pragma unroll 8
    for (int fc = 0; fc < 64; ++fc)
        c += pcount[(size_t)fc * N_OBJ + pt];      // coalesced byte loads
    float s = (c & 1) ? Dws[pt].w : 0.f;
#pragma unroll
    for (int off = 32; off > 0; off >>= 1) s += __shfl_down(s, off);
    if ((tid & 63) == 0) wsum[tid >> 6] = s;
    __syncthreads();
    if (tid == 0) {
        fpart[blockIdx.x] = wsum[0] + wsum[1] + wsum[2] + wsum[3];
        __threadfence();
        lastf = (atomicAdd(done, 1) == 31) ? 1 : 0;
        if (lastf) {
            float tot = 0.f;
            for (int i = 0; i < 32; ++i)
                tot += atomicAdd(&fpart[i], 0.f);  // coherent reads, fixed order
            out[0] = sqrtf(tot + 1e-12f);
        }
    }
}

extern "C" void kernel_launch(void* const* d_in, const int* in_sizes, int n_in,
                              void* d_out, int out_size, void* d_ws, size_t ws_size,
                              hipStream_t stream) {
    const float* obj = (const float*)d_in[0];
    const float* sr  = (const float*)d_in[1];
    const float* hv  = (const float*)d_in[2];
    const float* fn  = (const float*)d_in[3];
    const int*   hf  = (const int*)d_in[4];
    float* out = (float*)d_out;

    char* ws = (char*)d_ws;
    float4*        Dws    = (float4*)(ws + 0);         // 8192*16   = 128 KB
    float4*        F      = (float4*)(ws + 131072);    // 4096*4*16 = 256 KB
    unsigned char* pcount = (unsigned char*)(ws + 393216); // 64*8192 = 512 KB
    float*         fpart  = (float*)(ws + 917504);     // 128 B
    int*           done   = (int*)  (ws + 917632);     // 4 B

    nn_all<<<512, 256, 0, stream>>>(obj, sr, hv, fn, hf, out, Dws, F, done);
    ray_count<<<512, 256, 0, stream>>>(obj, Dws, F, pcount);
    finalize<<<32, 256, 0, stream>>>(Dws, pcount, fpart, done, out);
}